// Round 2
// baseline (649.728 us; speedup 1.0000x reference)
//
#include <hip/hip_runtime.h>
#include <hip/hip_bf16.h>
#include <math.h>

#define TT 8192
#define DDIM 1024
#define EE 8
#define FF 4096
#define CCAP 2048
#define NSLOT 16384

typedef __attribute__((ext_vector_type(4))) float f32x4;
typedef __attribute__((ext_vector_type(8))) short bf16x8;

typedef const __attribute__((address_space(1))) void CGV;
typedef __attribute__((address_space(3))) void LDSV;

__device__ __forceinline__ short f2bf(float f) {
  unsigned u = __builtin_bit_cast(unsigned, f);
  u += 0x7fffu + ((u >> 16) & 1u);
  return (short)(u >> 16);
}
__device__ __forceinline__ float bf2f(short s) {
  unsigned u = ((unsigned)(unsigned short)s) << 16;
  return __builtin_bit_cast(float, u);
}

// ---------------- gating: logits, top-2, normalized gates (f32) ----------------
__global__ void __launch_bounds__(256) gate_kernel(const float* __restrict__ x,
    const float* __restrict__ wg, int* __restrict__ idx1, int* __restrict__ idx2,
    float* __restrict__ g1s, float* __restrict__ g2s) {
  int lane = threadIdx.x & 63;
  int t = blockIdx.x * 4 + (threadIdx.x >> 6);
  const float* xr = x + (size_t)t * DDIM;
  float acc[8];
#pragma unroll
  for (int e = 0; e < 8; ++e) acc[e] = 0.f;
#pragma unroll
  for (int i = 0; i < 4; ++i) {
    int d = lane * 4 + i * 256;
    f32x4 xv = *(const f32x4*)(xr + d);
#pragma unroll
    for (int j = 0; j < 4; ++j) {
      const f32x4* wr = (const f32x4*)(wg + (size_t)(d + j) * 8);
      f32x4 w0 = wr[0], w1 = wr[1];
#pragma unroll
      for (int e = 0; e < 4; ++e) { acc[e] += xv[j] * w0[e]; acc[e + 4] += xv[j] * w1[e]; }
    }
  }
#pragma unroll
  for (int e = 0; e < 8; ++e) {
#pragma unroll
    for (int o = 32; o > 0; o >>= 1) acc[e] += __shfl_xor(acc[e], o, 64);
  }
  if (lane == 0) {
    int i1 = 0; float l1 = acc[0];
#pragma unroll
    for (int e = 1; e < 8; ++e) if (acc[e] > l1) { l1 = acc[e]; i1 = e; }
    int i2 = -1; float l2 = -3.0e38f;
#pragma unroll
    for (int e = 0; e < 8; ++e) if (e != i1 && acc[e] > l2) { l2 = acc[e]; i2 = e; }
    float e2 = expf(l2 - l1);           // <= 1, stable
    float inv = 1.f / (1.f + e2);
    idx1[t] = i1; idx2[t] = i2;
    g1s[t] = inv; g2s[t] = e2 * inv;    // == g1/(g1+g2), g2/(g1+g2)
  }
}

// ---------------- order-preserving slot assignment (GShard cumsum) ----------------
__global__ void __launch_bounds__(1024) scan_kernel(const int* __restrict__ idx1,
    const int* __restrict__ idx2, const float* __restrict__ g1s, const float* __restrict__ g2s,
    int* __restrict__ f1, int* __restrict__ f2, float* __restrict__ gg1, float* __restrict__ gg2,
    int* __restrict__ slot_token) {
  __shared__ unsigned long long slo[1024], shi[1024];
  int tid = threadIdx.x;
  for (int i = tid; i < NSLOT; i += 1024) slot_token[i] = -1;
  int t0 = tid * 8;
  int e1[8], e2[8];
#pragma unroll
  for (int i = 0; i < 8; ++i) { e1[i] = idx1[t0 + i]; e2[i] = idx2[t0 + i]; }

  unsigned long long lo = 0, hi = 0;
#pragma unroll
  for (int i = 0; i < 8; ++i) {
    int e = e1[i];
    if (e < 4) lo += 1ull << (16 * e); else hi += 1ull << (16 * (e - 4));
  }
  slo[tid] = lo; shi[tid] = hi; __syncthreads();
  for (int off = 1; off < 1024; off <<= 1) {
    unsigned long long alo = 0, ahi = 0;
    if (tid >= off) { alo = slo[tid - off]; ahi = shi[tid - off]; }
    __syncthreads();
    slo[tid] += alo; shi[tid] += ahi;
    __syncthreads();
  }
  unsigned long long exlo = slo[tid] - lo, exhi = shi[tid] - hi;
  unsigned long long tlo = slo[1023], thi = shi[1023];
  __syncthreads();
  int base1[8], tot1[8];
#pragma unroll
  for (int e = 0; e < 4; ++e) {
    base1[e]     = (int)((exlo >> (16 * e)) & 0xFFFF);
    base1[e + 4] = (int)((exhi >> (16 * e)) & 0xFFFF);
    tot1[e]      = (int)((tlo  >> (16 * e)) & 0xFFFF);
    tot1[e + 4]  = (int)((thi  >> (16 * e)) & 0xFFFF);
  }

  lo = 0; hi = 0;
#pragma unroll
  for (int i = 0; i < 8; ++i) {
    int e = e2[i];
    if (e < 4) lo += 1ull << (16 * e); else hi += 1ull << (16 * (e - 4));
  }
  slo[tid] = lo; shi[tid] = hi; __syncthreads();
  for (int off = 1; off < 1024; off <<= 1) {
    unsigned long long alo = 0, ahi = 0;
    if (tid >= off) { alo = slo[tid - off]; ahi = shi[tid - off]; }
    __syncthreads();
    slo[tid] += alo; shi[tid] += ahi;
    __syncthreads();
  }
  exlo = slo[tid] - lo; exhi = shi[tid] - hi;
  int base2[8];
#pragma unroll
  for (int e = 0; e < 4; ++e) {
    base2[e]     = (int)((exlo >> (16 * e)) & 0xFFFF);
    base2[e + 4] = (int)((exhi >> (16 * e)) & 0xFFFF);
  }

#pragma unroll
  for (int i = 0; i < 8; ++i) {
    int t = t0 + i;
    int a = e1[i];
    int p1 = base1[a]++;
    int k1 = (p1 < CCAP);
    int s1 = a * CCAP + (k1 ? p1 : CCAP - 1);
    f1[t] = s1;
    gg1[t] = k1 ? g1s[t] : 0.f;
    if (k1) slot_token[s1] = t;

    int b = e2[i];
    int p2 = base2[b] + tot1[b];
    base2[b]++;
    int k2 = (p2 < CCAP);
    int s2 = b * CCAP + (k2 ? p2 : CCAP - 1);
    f2[t] = s2;
    gg2[t] = k2 ? g2s[t] : 0.f;
    if (k2) slot_token[s2] = t;
  }
}

// ---------------- dispatch: gather token rows into slot rows (bf16) ----------------
__global__ void __launch_bounds__(128) dispatch_kernel(const float* __restrict__ x,
    const int* __restrict__ slot_token, short* __restrict__ disp) {
  int slot = blockIdx.x;
  int tid = threadIdx.x;
  int tok = slot_token[slot];
  short* dst = disp + (size_t)slot * DDIM + tid * 8;
  bf16x8 v;
  if (tok >= 0) {
    const float* src = x + (size_t)tok * DDIM + tid * 8;
    f32x4 a = *(const f32x4*)src;
    f32x4 b = *(const f32x4*)(src + 4);
#pragma unroll
    for (int j = 0; j < 4; ++j) { v[j] = f2bf(a[j]); v[j + 4] = f2bf(b[j]); }
  } else {
#pragma unroll
    for (int j = 0; j < 8; ++j) v[j] = 0;
  }
  *(bf16x8*)dst = v;
}

// ---------------- weight transpose + f32->bf16:  [E][R][Cc] -> [E][Cc][R] ----------------
__global__ void __launch_bounds__(256) tconv_kernel(const float* __restrict__ in,
    short* __restrict__ outp, int R, int Cc) {
  __shared__ float tl[32][33];
  long e = blockIdx.z;
  const float* src = in + e * (long)R * Cc;
  short* dst = outp + e * (long)R * Cc;
  int x0 = blockIdx.x * 32, y0 = blockIdx.y * 32;
  int tx = threadIdx.x, ty = threadIdx.y;
#pragma unroll
  for (int r = 0; r < 4; ++r)
    tl[ty * 4 + r][tx] = src[(long)(y0 + ty * 4 + r) * Cc + x0 + tx];
  __syncthreads();
#pragma unroll
  for (int r = 0; r < 4; ++r)
    dst[(long)(x0 + ty * 4 + r) * R + y0 + tx] = f2bf(tl[tx][ty * 4 + r]);
}

// ---------------- bf16 GEMM: 256x256 tile, BK=32, 3-slot LDS ring, counted vmcnt ----
// A: [M][K] (lda=LDA), B: [N][K] (ldb=LDB), C: [M][N] (ldc=LDC), bf16 in/out, f32 acc.
// 512 threads = 8 waves (2M x 4N); per wave 128x64 output = acc[8][4] f32x4.
// Schedule per K-tile t: stage tile t+3 into slot[t%3] (reads of tile t finished last
// iter, enforced by lgkmcnt(0)+barrier); ds_read frags of tile t+1 from slot[(t+1)%3]
// (landed: vmcnt(4) invariant); MFMA tile t from regs; lgkmcnt(0); vmcnt(4); barrier.
// No vmcnt(0) drain in the main loop (T4).
template<int KD, int LDA, int LDB, int LDC, bool GELU>
__global__ void __launch_bounds__(512) gemm256(const short* __restrict__ Ag,
    const short* __restrict__ Bg, short* __restrict__ Cg,
    long aes, long bes, long ces, int nbx, int nby) {
  constexpr int KT = KD / 32;
  __shared__ alignas(16) short As[3][256 * 32];
  __shared__ alignas(16) short Bs[3][256 * 32];

  // T1: bijective XCD swizzle (gridDim.x % 8 == 0 for all launches here)
  int bid = blockIdx.x;
  int wid = (bid & 7) * ((int)gridDim.x >> 3) + (bid >> 3);
  int bx = wid % nbx;
  int rem = wid / nbx;
  int by = rem % nby;
  int e  = rem / nby;

  const short* A = Ag + (long)e * aes + (long)by * 256 * LDA;
  const short* B = Bg + (long)e * bes + (long)bx * 256 * LDB;
  short* Cp = Cg + (long)e * ces + (long)by * 256 * LDC + bx * 256;

  int tid = threadIdx.x;
  int l = tid & 63;
  int w = tid >> 6;
  int wm = w >> 2, wn = w & 3;          // 2 x 4 wave grid

  f32x4 acc[8][4];
#pragma unroll
  for (int m = 0; m < 8; ++m)
#pragma unroll
    for (int n = 0; n < 4; ++n)
#pragma unroll
      for (int r = 0; r < 4; ++r) acc[m][n][r] = 0.f;

  // staging: tile 256x32 bf16 = 1024 granules of 16B per matrix; 2 A + 2 B per thread
  auto STAGE = [&](int slot, int k0) {
#pragma unroll
    for (int c = 0; c < 2; ++c) {
      int g = c * 512 + tid;
      int r = g >> 2, col = (g & 3) * 8;
      __builtin_amdgcn_global_load_lds((CGV*)(A + (long)r * LDA + k0 + col),
                                       (LDSV*)(&As[slot][g * 8]), 16, 0, 0);
      __builtin_amdgcn_global_load_lds((CGV*)(B + (long)r * LDB + k0 + col),
                                       (LDSV*)(&Bs[slot][g * 8]), 16, 0, 0);
    }
  };

  int abase = (wm * 128 + (l & 15)) * 32 + (l >> 4) * 8;
  int bbase = (wn * 64 + (l & 15)) * 32 + (l >> 4) * 8;
  auto DSREAD = [&](bf16x8* fa, bf16x8* fb, int slot) {
    const short* a = &As[slot][abase];
    const short* b = &Bs[slot][bbase];
#pragma unroll
    for (int m = 0; m < 8; ++m) fa[m] = *(const bf16x8*)(a + m * 512);
#pragma unroll
    for (int n = 0; n < 4; ++n) fb[n] = *(const bf16x8*)(b + n * 512);
  };
  auto MFMA = [&](bf16x8* fa, bf16x8* fb) {
    __builtin_amdgcn_s_setprio(1);
#pragma unroll
    for (int m = 0; m < 8; ++m)
#pragma unroll
      for (int n = 0; n < 4; ++n)
        acc[m][n] = __builtin_amdgcn_mfma_f32_16x16x32_bf16(fa[m], fb[n], acc[m][n], 0, 0, 0);
    __builtin_amdgcn_s_setprio(0);
  };

  bf16x8 fA0[8], fB0[4], fA1[8], fB1[4];

  // prologue: stage tiles 0,1,2; wait t0,t1; read frags t0; fence reads before loop
  STAGE(0, 0); STAGE(1, 32); STAGE(2, 64);
  asm volatile("s_waitcnt vmcnt(4)" ::: "memory");   // t0,t1 landed (t2's 4 in flight)
  __builtin_amdgcn_sched_barrier(0);
  __builtin_amdgcn_s_barrier();
  __builtin_amdgcn_sched_barrier(0);
  DSREAD(fA0, fB0, 0);
  asm volatile("s_waitcnt lgkmcnt(0)" ::: "memory");
  __builtin_amdgcn_sched_barrier(0);
  __builtin_amdgcn_s_barrier();                      // all waves done reading slot0
  __builtin_amdgcn_sched_barrier(0);

  int sl = 0;   // t % 3
  auto ITER = [&](int t, bf16x8* fcA, bf16x8* fcB, bf16x8* fnA, bf16x8* fnB) {
    if (t + 3 < KT) STAGE(sl, (t + 3) * 32);
    int rs = (sl == 2) ? 0 : sl + 1;
    if (t + 1 < KT) DSREAD(fnA, fnB, rs);
    MFMA(fcA, fcB);
    asm volatile("s_waitcnt lgkmcnt(0)" ::: "memory");  // my frag reads complete
    __builtin_amdgcn_sched_barrier(0);
    if (t + 3 < KT) { asm volatile("s_waitcnt vmcnt(4)" ::: "memory"); }
    else            { asm volatile("s_waitcnt vmcnt(0)" ::: "memory"); }
    __builtin_amdgcn_sched_barrier(0);
    __builtin_amdgcn_s_barrier();
    __builtin_amdgcn_sched_barrier(0);
    sl = (sl == 2) ? 0 : sl + 1;
  };

  for (int t = 0; t < KT; t += 2) {
    ITER(t,     fA0, fB0, fA1, fB1);
    ITER(t + 1, fA1, fB1, fA0, fB0);
  }

  // epilogue
#pragma unroll
  for (int m = 0; m < 8; ++m) {
    int gr0 = wm * 128 + m * 16 + (l >> 4) * 4;
#pragma unroll
    for (int r = 0; r < 4; ++r) {
#pragma unroll
      for (int n = 0; n < 4; ++n) {
        float v = acc[m][n][r];
        if (GELU) v = 0.5f * v * (1.f + erff(v * 0.70710678118654752f));
        Cp[(long)(gr0 + r) * LDC + wn * 64 + n * 16 + (l & 15)] = f2bf(v);
      }
    }
  }
}

// ---------------- combine: out[t] = gg1*eo[f1] + gg2*eo[f2] (f32 out) ----------------
__global__ void __launch_bounds__(128) combine_kernel(const short* __restrict__ eo,
    const int* __restrict__ f1, const int* __restrict__ f2,
    const float* __restrict__ gg1, const float* __restrict__ gg2, float* __restrict__ out) {
  int t = blockIdx.x, tid = threadIdx.x;
  float a = gg1[t], b = gg2[t];
  long s1 = f1[t], s2 = f2[t];
  bf16x8 v1 = *(const bf16x8*)(eo + s1 * DDIM + tid * 8);
  bf16x8 v2 = *(const bf16x8*)(eo + s2 * DDIM + tid * 8);
  f32x4 o0, o1;
#pragma unroll
  for (int j = 0; j < 4; ++j) {
    o0[j] = a * bf2f(v1[j])     + b * bf2f(v2[j]);
    o1[j] = a * bf2f(v1[j + 4]) + b * bf2f(v2[j + 4]);
  }
  float* dst = out + (size_t)t * DDIM + tid * 8;
  *(f32x4*)dst = o0;
  *(f32x4*)(dst + 4) = o1;
}

extern "C" void kernel_launch(void* const* d_in, const int* in_sizes, int n_in,
                              void* d_out, int out_size, void* d_ws, size_t ws_size,
                              hipStream_t stream) {
  const float* x      = (const float*)d_in[0];
  const float* wg     = (const float*)d_in[1];
  const float* w_gate = (const float*)d_in[2];
  const float* w_down = (const float*)d_in[3];
  float* out = (float*)d_out;

  char* ws = (char*)d_ws;
  size_t off = 0;
  auto alloc = [&](size_t bytes) -> void* {
    void* p = ws + off;
    off += (bytes + 255) & ~(size_t)255;
    return p;
  };
  short* wbg  = (short*)alloc((size_t)EE * FF * DDIM * 2);   // [E][F][D] bf16
  short* wbd  = (short*)alloc((size_t)EE * DDIM * FF * 2);   // [E][D][F] bf16
  short* disp = (short*)alloc((size_t)NSLOT * DDIM * 2);
  short* eo   = (short*)alloc((size_t)NSLOT * DDIM * 2);
  int*   idx1 = (int*)alloc(TT * 4);
  int*   idx2 = (int*)alloc(TT * 4);
  int*   f1   = (int*)alloc(TT * 4);
  int*   f2   = (int*)alloc(TT * 4);
  float* g1s  = (float*)alloc(TT * 4);
  float* g2s  = (float*)alloc(TT * 4);
  float* gg1  = (float*)alloc(TT * 4);
  float* gg2  = (float*)alloc(TT * 4);
  int*   slot_token = (int*)alloc(NSLOT * 4);
  size_t h_full = (size_t)NSLOT * FF * 2;
  bool full = (off + h_full) <= ws_size;
  short* h = (short*)(ws + off);

  // weights -> bf16, transposed to [N][K]
  tconv_kernel<<<dim3(FF / 32, DDIM / 32, EE), dim3(32, 8), 0, stream>>>(w_gate, wbg, DDIM, FF);
  tconv_kernel<<<dim3(DDIM / 32, FF / 32, EE), dim3(32, 8), 0, stream>>>(w_down, wbd, FF, DDIM);

  gate_kernel<<<TT / 4, 256, 0, stream>>>(x, wg, idx1, idx2, g1s, g2s);
  scan_kernel<<<1, 1024, 0, stream>>>(idx1, idx2, g1s, g2s, f1, f2, gg1, gg2, slot_token);
  dispatch_kernel<<<NSLOT, 128, 0, stream>>>(x, slot_token, disp);

  if (full) {
    gemm256<DDIM, DDIM, DDIM, FF, true><<<(FF / 256) * (CCAP / 256) * EE, 512, 0, stream>>>(
        disp, wbg, h, (long)CCAP * DDIM, (long)FF * DDIM, (long)CCAP * FF, FF / 256, CCAP / 256);
    gemm256<FF, FF, FF, DDIM, false><<<(DDIM / 256) * (CCAP / 256) * EE, 512, 0, stream>>>(
        h, wbd, eo, (long)CCAP * FF, (long)DDIM * FF, (long)CCAP * DDIM, DDIM / 256, CCAP / 256);
  } else {
    for (int e = 0; e < EE; ++e) {
      gemm256<DDIM, DDIM, DDIM, FF, true><<<(FF / 256) * (CCAP / 256), 512, 0, stream>>>(
          disp + (long)e * CCAP * DDIM, wbg + (long)e * FF * DDIM, h, 0, 0, 0, FF / 256, CCAP / 256);
      gemm256<FF, FF, FF, DDIM, false><<<(DDIM / 256) * (CCAP / 256), 512, 0, stream>>>(
          h, wbd + (long)e * DDIM * FF, eo + (long)e * CCAP * DDIM, 0, 0, 0, DDIM / 256, CCAP / 256);
    }
  }

  combine_kernel<<<TT, 128, 0, stream>>>(eo, f1, f2, gg1, gg2, out);
}

// Round 3
// 536.154 us; speedup vs baseline: 1.2118x; 1.2118x over previous
//
#include <hip/hip_runtime.h>
#include <hip/hip_bf16.h>
#include <math.h>

#define TT 8192
#define DDIM 1024
#define EE 8
#define FF 4096
#define CCAP 2048
#define NSLOT 16384

typedef __attribute__((ext_vector_type(4))) float f32x4;
typedef __attribute__((ext_vector_type(8))) short bf16x8;

typedef const __attribute__((address_space(1))) void CGV;
typedef __attribute__((address_space(3))) void LDSV;

#define LGKM(n) do { asm volatile("s_waitcnt lgkmcnt(" #n ")" ::: "memory"); \
                     __builtin_amdgcn_sched_barrier(0); } while (0)
#define VMC(n)  do { asm volatile("s_waitcnt vmcnt(" #n ")" ::: "memory"); \
                     __builtin_amdgcn_sched_barrier(0); } while (0)
#define BAR()   do { __builtin_amdgcn_sched_barrier(0); __builtin_amdgcn_s_barrier(); \
                     __builtin_amdgcn_sched_barrier(0); } while (0)

__device__ __forceinline__ short f2bf(float f) {
  unsigned u = __builtin_bit_cast(unsigned, f);
  u += 0x7fffu + ((u >> 16) & 1u);
  return (short)(u >> 16);
}
__device__ __forceinline__ float bf2f(short s) {
  unsigned u = ((unsigned)(unsigned short)s) << 16;
  return __builtin_bit_cast(float, u);
}

// ---------------- gating: logits, top-2, normalized gates (f32) ----------------
__global__ void __launch_bounds__(256) gate_kernel(const float* __restrict__ x,
    const float* __restrict__ wg, int* __restrict__ idx1, int* __restrict__ idx2,
    float* __restrict__ g1s, float* __restrict__ g2s) {
  int lane = threadIdx.x & 63;
  int t = blockIdx.x * 4 + (threadIdx.x >> 6);
  const float* xr = x + (size_t)t * DDIM;
  float acc[8];
#pragma unroll
  for (int e = 0; e < 8; ++e) acc[e] = 0.f;
#pragma unroll
  for (int i = 0; i < 4; ++i) {
    int d = lane * 4 + i * 256;
    f32x4 xv = *(const f32x4*)(xr + d);
#pragma unroll
    for (int j = 0; j < 4; ++j) {
      const f32x4* wr = (const f32x4*)(wg + (size_t)(d + j) * 8);
      f32x4 w0 = wr[0], w1 = wr[1];
#pragma unroll
      for (int e = 0; e < 4; ++e) { acc[e] += xv[j] * w0[e]; acc[e + 4] += xv[j] * w1[e]; }
    }
  }
#pragma unroll
  for (int e = 0; e < 8; ++e) {
#pragma unroll
    for (int o = 32; o > 0; o >>= 1) acc[e] += __shfl_xor(acc[e], o, 64);
  }
  if (lane == 0) {
    int i1 = 0; float l1 = acc[0];
#pragma unroll
    for (int e = 1; e < 8; ++e) if (acc[e] > l1) { l1 = acc[e]; i1 = e; }
    int i2 = -1; float l2 = -3.0e38f;
#pragma unroll
    for (int e = 0; e < 8; ++e) if (e != i1 && acc[e] > l2) { l2 = acc[e]; i2 = e; }
    float e2 = expf(l2 - l1);           // <= 1, stable
    float inv = 1.f / (1.f + e2);
    idx1[t] = i1; idx2[t] = i2;
    g1s[t] = inv; g2s[t] = e2 * inv;    // == g1/(g1+g2), g2/(g1+g2)
  }
}

// ---------------- order-preserving slot assignment (GShard cumsum) ----------------
__global__ void __launch_bounds__(1024) scan_kernel(const int* __restrict__ idx1,
    const int* __restrict__ idx2, const float* __restrict__ g1s, const float* __restrict__ g2s,
    int* __restrict__ f1, int* __restrict__ f2, float* __restrict__ gg1, float* __restrict__ gg2,
    int* __restrict__ slot_token) {
  __shared__ unsigned long long slo[1024], shi[1024];
  int tid = threadIdx.x;
  for (int i = tid; i < NSLOT; i += 1024) slot_token[i] = -1;
  int t0 = tid * 8;
  int e1[8], e2[8];
#pragma unroll
  for (int i = 0; i < 8; ++i) { e1[i] = idx1[t0 + i]; e2[i] = idx2[t0 + i]; }

  unsigned long long lo = 0, hi = 0;
#pragma unroll
  for (int i = 0; i < 8; ++i) {
    int e = e1[i];
    if (e < 4) lo += 1ull << (16 * e); else hi += 1ull << (16 * (e - 4));
  }
  slo[tid] = lo; shi[tid] = hi; __syncthreads();
  for (int off = 1; off < 1024; off <<= 1) {
    unsigned long long alo = 0, ahi = 0;
    if (tid >= off) { alo = slo[tid - off]; ahi = shi[tid - off]; }
    __syncthreads();
    slo[tid] += alo; shi[tid] += ahi;
    __syncthreads();
  }
  unsigned long long exlo = slo[tid] - lo, exhi = shi[tid] - hi;
  unsigned long long tlo = slo[1023], thi = shi[1023];
  __syncthreads();
  int base1[8], tot1[8];
#pragma unroll
  for (int e = 0; e < 4; ++e) {
    base1[e]     = (int)((exlo >> (16 * e)) & 0xFFFF);
    base1[e + 4] = (int)((exhi >> (16 * e)) & 0xFFFF);
    tot1[e]      = (int)((tlo  >> (16 * e)) & 0xFFFF);
    tot1[e + 4]  = (int)((thi  >> (16 * e)) & 0xFFFF);
  }

  lo = 0; hi = 0;
#pragma unroll
  for (int i = 0; i < 8; ++i) {
    int e = e2[i];
    if (e < 4) lo += 1ull << (16 * e); else hi += 1ull << (16 * (e - 4));
  }
  slo[tid] = lo; shi[tid] = hi; __syncthreads();
  for (int off = 1; off < 1024; off <<= 1) {
    unsigned long long alo = 0, ahi = 0;
    if (tid >= off) { alo = slo[tid - off]; ahi = shi[tid - off]; }
    __syncthreads();
    slo[tid] += alo; shi[tid] += ahi;
    __syncthreads();
  }
  exlo = slo[tid] - lo; exhi = shi[tid] - hi;
  int base2[8];
#pragma unroll
  for (int e = 0; e < 4; ++e) {
    base2[e]     = (int)((exlo >> (16 * e)) & 0xFFFF);
    base2[e + 4] = (int)((exhi >> (16 * e)) & 0xFFFF);
  }

#pragma unroll
  for (int i = 0; i < 8; ++i) {
    int t = t0 + i;
    int a = e1[i];
    int p1 = base1[a]++;
    int k1 = (p1 < CCAP);
    int s1 = a * CCAP + (k1 ? p1 : CCAP - 1);
    f1[t] = s1;
    gg1[t] = k1 ? g1s[t] : 0.f;
    if (k1) slot_token[s1] = t;

    int b = e2[i];
    int p2 = base2[b] + tot1[b];
    base2[b]++;
    int k2 = (p2 < CCAP);
    int s2 = b * CCAP + (k2 ? p2 : CCAP - 1);
    f2[t] = s2;
    gg2[t] = k2 ? g2s[t] : 0.f;
    if (k2) slot_token[s2] = t;
  }
}

// ---------------- dispatch: gather token rows into slot rows (bf16) ----------------
__global__ void __launch_bounds__(128) dispatch_kernel(const float* __restrict__ x,
    const int* __restrict__ slot_token, short* __restrict__ disp) {
  int slot = blockIdx.x;
  int tid = threadIdx.x;
  int tok = slot_token[slot];
  short* dst = disp + (size_t)slot * DDIM + tid * 8;
  bf16x8 v;
  if (tok >= 0) {
    const float* src = x + (size_t)tok * DDIM + tid * 8;
    f32x4 a = *(const f32x4*)src;
    f32x4 b = *(const f32x4*)(src + 4);
#pragma unroll
    for (int j = 0; j < 4; ++j) { v[j] = f2bf(a[j]); v[j + 4] = f2bf(b[j]); }
  } else {
#pragma unroll
    for (int j = 0; j < 8; ++j) v[j] = 0;
  }
  *(bf16x8*)dst = v;
}

// ---------------- weight transpose + f32->bf16:  [E][R][Cc] -> [E][Cc][R] ----------------
__global__ void __launch_bounds__(256) tconv_kernel(const float* __restrict__ in,
    short* __restrict__ outp, int R, int Cc) {
  __shared__ float tl[32][33];
  long e = blockIdx.z;
  const float* src = in + e * (long)R * Cc;
  short* dst = outp + e * (long)R * Cc;
  int x0 = blockIdx.x * 32, y0 = blockIdx.y * 32;
  int tx = threadIdx.x, ty = threadIdx.y;
#pragma unroll
  for (int r = 0; r < 4; ++r)
    tl[ty * 4 + r][tx] = src[(long)(y0 + ty * 4 + r) * Cc + x0 + tx];
  __syncthreads();
#pragma unroll
  for (int r = 0; r < 4; ++r)
    dst[(long)(x0 + ty * 4 + r) * R + y0 + tx] = f2bf(tl[tx][ty * 4 + r]);
}

// ===== bf16 GEMM, 256x256 tile, BK=64, 8-phase schedule (m201/m248 template) =====
// A: [M][K] (lda=LDA), B: [N][K] (ldb=LDB), C: [M][N] (ldc=LDC). 512 thr = 8 waves
// (2M x 4N), per-wave 128x64 out. LDS 128KB: [buf][A/B][half][128x64] bf16, T2
// swizzle byte^=(row&7)<<4 (linear gload_lds dest + pre-swizzled global source +
// swizzled ds_read). 8 phases / 2 K-tiles per iter; per phase: ds-read subtile,
// stage 1 half-tile, barrier, lgkm(0), 16 MFMA (setprio), barrier. Counted vmcnt(4)
// at phases 4 & 8 only (tail: vmcnt(0)).
template<int KD, int LDA, int LDB, int LDC, bool GELU>
__global__ void __launch_bounds__(512, 2) gemm8p(const short* __restrict__ Ag,
    const short* __restrict__ Bg, short* __restrict__ Cg,
    long aes, long bes, long ces, int nbx, int nby) {
  constexpr int KT = KD / 64;              // K-tiles of 64
  __shared__ alignas(16) short lds[2][2][2][128 * 64];  // [buf][mat][half]

  int bid = blockIdx.x;
  int wid = (bid & 7) * ((int)gridDim.x >> 3) + (bid >> 3);   // T1 (grid%8==0)
  int bx = wid % nbx;
  int rem = wid / nbx;
  int by = rem % nby;
  int e  = rem / nby;

  const short* A = Ag + (long)e * aes + (long)by * 256 * LDA;
  const short* B = Bg + (long)e * bes + (long)bx * 256 * LDB;
  short* Cp = Cg + (long)e * ces + (long)by * 256 * LDC + bx * 256;

  int tid = threadIdx.x;
  int l = tid & 63;
  int w = tid >> 6;
  int wm = w >> 2, wn = w & 3;             // 2 x 4 wave grid

  f32x4 acc[8][4];
#pragma unroll
  for (int m = 0; m < 8; ++m)
#pragma unroll
    for (int n = 0; n < 4; ++n)
#pragma unroll
      for (int r = 0; r < 4; ++r) acc[m][n][r] = 0.f;

  // stage one half-tile (128 rows x 64 k) : 2 x global_load_lds per thread.
  // LDS dest linear (granule g = row*8+slot); global source slot pre-swizzled.
  auto STAGE = [&](const short* G, int LD, short* base, int kt) {
#pragma unroll
    for (int c = 0; c < 2; ++c) {
      int g = c * 512 + tid;
      int row = g >> 3, sl = g & 7;
      int col = kt * 64 + ((sl ^ (row & 7)) << 3);
      __builtin_amdgcn_global_load_lds((CGV*)(G + (long)row * LD + col),
                                       (LDSV*)(base + g * 8), 16, 0, 0);
    }
  };

  // frag reads with matching swizzle
  auto RDA = [&](bf16x8* f, const short* hb, int qm) {
#pragma unroll
    for (int mm = 0; mm < 4; ++mm) {
      int row = qm * 64 + mm * 16 + (l & 15);
      const char* rp = (const char*)hb + row * 128;
      int swz = (row & 7) << 4;
#pragma unroll
      for (int ks = 0; ks < 2; ++ks) {
        int off = ((ks * 4 + (l >> 4)) << 4) ^ swz;
        f[mm * 2 + ks] = *(const bf16x8*)(rp + off);
      }
    }
  };
  auto RDB = [&](bf16x8* f, const short* hb, int qn) {
#pragma unroll
    for (int nn = 0; nn < 2; ++nn) {
      int row = (wn & 1) * 64 + qn * 32 + nn * 16 + (l & 15);
      const char* rp = (const char*)hb + row * 128;
      int swz = (row & 7) << 4;
#pragma unroll
      for (int ks = 0; ks < 2; ++ks) {
        int off = ((ks * 4 + (l >> 4)) << 4) ^ swz;
        f[nn * 2 + ks] = *(const bf16x8*)(rp + off);
      }
    }
  };
  auto MF = [&](bf16x8* fa, bf16x8* fb, int qm, int qn) {
    __builtin_amdgcn_s_setprio(1);
#pragma unroll
    for (int mm = 0; mm < 4; ++mm)
#pragma unroll
      for (int nn = 0; nn < 2; ++nn)
#pragma unroll
        for (int ks = 0; ks < 2; ++ks)
          acc[qm * 4 + mm][qn * 2 + nn] = __builtin_amdgcn_mfma_f32_16x16x32_bf16(
              fa[mm * 2 + ks], fb[nn * 2 + ks], acc[qm * 4 + mm][qn * 2 + nn], 0, 0, 0);
    __builtin_amdgcn_s_setprio(0);
  };

  short* A0b[2] = { &lds[0][0][0][0], &lds[1][0][0][0] };
  short* A1b[2] = { &lds[0][0][1][0], &lds[1][0][1][0] };
  short* B0b[2] = { &lds[0][1][0][0], &lds[1][1][0][0] };
  short* B1b[2] = { &lds[0][1][1][0], &lds[1][1][1][0] };
  const short* Ah = A + (long)128 * LDA;   // A half1 global base
  const short* Bh = B + (long)128 * LDB;
  const short* Ard[2] = { &lds[0][0][wm][0], &lds[1][0][wm][0] };   // wave's read bases
  const short* Brd[2] = { &lds[0][1][wn >> 1][0], &lds[1][1][wn >> 1][0] };

  bf16x8 a0[8], a1[8], b0[4], b1[4];

  // prologue: A0(0) A1(0) B0(0) B1(0) -> buf0; A0(1) A1(1) -> buf1
  STAGE(A, LDA, A0b[0], 0); STAGE(Ah, LDA, A1b[0], 0);
  STAGE(B, LDB, B0b[0], 0); STAGE(Bh, LDB, B1b[0], 0);
  STAGE(A, LDA, A0b[1], 1); STAGE(Ah, LDA, A1b[1], 1);
  VMC(4);                    // tile 0 fully landed
  BAR();

  for (int i = 0; i < KT / 2; ++i) {
    int v = 2 * i + 1, x = 2 * i + 3;
    int wk = 2 * i + 2;
    bool sw = wk < KT, sx = x < KT;
    // ---- P1: rd a0,b0 (tile u, buf0); stage B0(v)->buf1
    RDA(a0, Ard[0], 0); RDB(b0, Brd[0], 0);
    STAGE(B, LDB, B0b[1], v);
    LGKM(8);
    BAR(); LGKM(0);
    MF(a0, b0, 0, 0);
    BAR();
    // ---- P2: rd a1; stage B1(v)->buf1
    RDA(a1, Ard[0], 1);
    STAGE(Bh, LDB, B1b[1], v);
    BAR(); LGKM(0);
    MF(a1, b0, 1, 0);
    BAR();
    // ---- P3: rd b1; stage A0(w)->buf0
    RDB(b1, Brd[0], 1);
    if (sw) STAGE(A, LDA, A0b[0], wk);
    BAR(); LGKM(0);
    MF(a0, b1, 0, 1);
    BAR();
    // ---- P4: stage A1(w)->buf0; counted vmcnt
    if (sw) { STAGE(Ah, LDA, A1b[0], wk); VMC(4); }
    else    { VMC(0); }
    BAR();
    MF(a1, b1, 1, 1);
    BAR();
    // ---- P5: rd a0,b0 (tile v, buf1); stage B0(w)->buf0
    RDA(a0, Ard[1], 0); RDB(b0, Brd[1], 0);
    if (sw) STAGE(B, LDB, B0b[0], wk);
    LGKM(8);
    BAR(); LGKM(0);
    MF(a0, b0, 0, 0);
    BAR();
    // ---- P6: rd a1; stage B1(w)->buf0
    RDA(a1, Ard[1], 1);
    if (sw) STAGE(Bh, LDB, B1b[0], wk);
    BAR(); LGKM(0);
    MF(a1, b0, 1, 0);
    BAR();
    // ---- P7: rd b1; stage A0(x)->buf1
    RDB(b1, Brd[1], 1);
    if (sx) STAGE(A, LDA, A0b[1], x);
    BAR(); LGKM(0);
    MF(a0, b1, 0, 1);
    BAR();
    // ---- P8: stage A1(x)->buf1; counted vmcnt
    if (sx) { STAGE(Ah, LDA, A1b[1], x); VMC(4); }
    else    { VMC(0); }
    BAR();
    MF(a1, b1, 1, 1);
    BAR();
  }

  // epilogue
#pragma unroll
  for (int m = 0; m < 8; ++m) {
    int gr0 = wm * 128 + m * 16 + (l >> 4) * 4;
#pragma unroll
    for (int r = 0; r < 4; ++r) {
#pragma unroll
      for (int n = 0; n < 4; ++n) {
        float vv = acc[m][n][r];
        if (GELU) vv = 0.5f * vv * (1.f + erff(vv * 0.70710678118654752f));
        Cp[(long)(gr0 + r) * LDC + wn * 64 + n * 16 + (l & 15)] = f2bf(vv);
      }
    }
  }
}

// ---------------- combine: out[t] = gg1*eo[f1] + gg2*eo[f2] (f32 out) ----------------
__global__ void __launch_bounds__(128) combine_kernel(const short* __restrict__ eo,
    const int* __restrict__ f1, const int* __restrict__ f2,
    const float* __restrict__ gg1, const float* __restrict__ gg2, float* __restrict__ out) {
  int t = blockIdx.x, tid = threadIdx.x;
  float a = gg1[t], b = gg2[t];
  long s1 = f1[t], s2 = f2[t];
  bf16x8 v1 = *(const bf16x8*)(eo + s1 * DDIM + tid * 8);
  bf16x8 v2 = *(const bf16x8*)(eo + s2 * DDIM + tid * 8);
  f32x4 o0, o1;
#pragma unroll
  for (int j = 0; j < 4; ++j) {
    o0[j] = a * bf2f(v1[j])     + b * bf2f(v2[j]);
    o1[j] = a * bf2f(v1[j + 4]) + b * bf2f(v2[j + 4]);
  }
  float* dst = out + (size_t)t * DDIM + tid * 8;
  *(f32x4*)dst = o0;
  *(f32x4*)(dst + 4) = o1;
}

extern "C" void kernel_launch(void* const* d_in, const int* in_sizes, int n_in,
                              void* d_out, int out_size, void* d_ws, size_t ws_size,
                              hipStream_t stream) {
  const float* x      = (const float*)d_in[0];
  const float* wg     = (const float*)d_in[1];
  const float* w_gate = (const float*)d_in[2];
  const float* w_down = (const float*)d_in[3];
  float* out = (float*)d_out;

  char* ws = (char*)d_ws;
  size_t off = 0;
  auto alloc = [&](size_t bytes) -> void* {
    void* p = ws + off;
    off += (bytes + 255) & ~(size_t)255;
    return p;
  };
  short* wbg  = (short*)alloc((size_t)EE * FF * DDIM * 2);   // [E][F][D] bf16
  short* wbd  = (short*)alloc((size_t)EE * DDIM * FF * 2);   // [E][D][F] bf16
  short* disp = (short*)alloc((size_t)NSLOT * DDIM * 2);
  short* eo   = (short*)alloc((size_t)NSLOT * DDIM * 2);
  int*   idx1 = (int*)alloc(TT * 4);
  int*   idx2 = (int*)alloc(TT * 4);
  int*   f1   = (int*)alloc(TT * 4);
  int*   f2   = (int*)alloc(TT * 4);
  float* g1s  = (float*)alloc(TT * 4);
  float* g2s  = (float*)alloc(TT * 4);
  float* gg1  = (float*)alloc(TT * 4);
  float* gg2  = (float*)alloc(TT * 4);
  int*   slot_token = (int*)alloc(NSLOT * 4);
  size_t h_full = (size_t)NSLOT * FF * 2;
  bool full = (off + h_full) <= ws_size;
  short* h = (short*)(ws + off);

  // weights -> bf16, transposed to [N][K]
  tconv_kernel<<<dim3(FF / 32, DDIM / 32, EE), dim3(32, 8), 0, stream>>>(w_gate, wbg, DDIM, FF);
  tconv_kernel<<<dim3(DDIM / 32, FF / 32, EE), dim3(32, 8), 0, stream>>>(w_down, wbd, FF, DDIM);

  gate_kernel<<<TT / 4, 256, 0, stream>>>(x, wg, idx1, idx2, g1s, g2s);
  scan_kernel<<<1, 1024, 0, stream>>>(idx1, idx2, g1s, g2s, f1, f2, gg1, gg2, slot_token);
  dispatch_kernel<<<NSLOT, 128, 0, stream>>>(x, slot_token, disp);

  if (full) {
    gemm8p<DDIM, DDIM, DDIM, FF, true><<<(FF / 256) * (CCAP / 256) * EE, 512, 0, stream>>>(
        disp, wbg, h, (long)CCAP * DDIM, (long)FF * DDIM, (long)CCAP * FF, FF / 256, CCAP / 256);
    gemm8p<FF, FF, FF, DDIM, false><<<(DDIM / 256) * (CCAP / 256) * EE, 512, 0, stream>>>(
        h, wbd, eo, (long)CCAP * FF, (long)DDIM * FF, (long)CCAP * DDIM, DDIM / 256, CCAP / 256);
  } else {
    for (int e = 0; e < EE; ++e) {
      gemm8p<DDIM, DDIM, DDIM, FF, true><<<(FF / 256) * (CCAP / 256), 512, 0, stream>>>(
          disp + (long)e * CCAP * DDIM, wbg + (long)e * FF * DDIM, h, 0, 0, 0, FF / 256, CCAP / 256);
      gemm8p<FF, FF, FF, DDIM, false><<<(DDIM / 256) * (CCAP / 256), 512, 0, stream>>>(
          h, wbd + (long)e * DDIM * FF, eo + (long)e * CCAP * DDIM, 0, 0, 0, DDIM / 256, CCAP / 256);
    }
  }

  combine_kernel<<<TT, 128, 0, stream>>>(eo, f1, f2, gg1, gg2, out);
}